// Round 7
// baseline (473.482 us; speedup 1.0000x reference)
//
#include <hip/hip_runtime.h>
#include <math.h>

#define D_MODEL 512
#define BATCH 8
#define SEQ 512
#define HEAD 64
#define DK 4
#define DV 8
#define HIDD 10

// proj tiled-GEMM params
#define MR 64    // rows per block
#define KC 32    // k-chunk
#define NC 256   // cols per block

// ---------------------------------------------------------------------------
// Projection as tiled GEMM: [4096 x 512] @ [512 x 1024] -> {Q2|K2|V2},
// head-major outputs: Q2/K2 = [b][h][s][4], V2 = [b][h][s][8].
// 256 threads; thread = rt (8 rows) x ct (cols {ct*4..+3, 128+ct*4..+3}).
// Split-pair cols -> W reads are 16B-lane-stride b128 = conflict-free
// (fixes R6's 4.2M bank-conflict cycles). Register prefetch of the next
// k-chunk hides global latency across the barriers (1 block/CU).
// Per k: 2 W b128 + 2 x b128 (wave-broadcast) feed 64 FMA.
// ---------------------------------------------------------------------------
__global__ __launch_bounds__(256) void proj_kernel(
    const float* __restrict__ xq, const float* __restrict__ xkv,
    const float* __restrict__ Wq, const float* __restrict__ Wk,
    const float* __restrict__ Wv,
    float* __restrict__ Q2, float* __restrict__ K2, float* __restrict__ V2)
{
    __shared__ float xt[KC * MR];   // [k][r]  8 KB
    __shared__ float wt[KC * NC];   // [k][c] 32 KB

    const int t  = threadIdx.x;
    const int bj = blockIdx.x & 3;
    const int br = blockIdx.x >> 2;
    const int r0 = br * MR;

    const float* X; const float* W; int ldw; int c0;
    if (bj == 0)      { X = xq;  W = Wq; ldw = 256; c0 = 0;   }
    else if (bj == 1) { X = xkv; W = Wk; ldw = 256; c0 = 0;   }
    else if (bj == 2) { X = xkv; W = Wv; ldw = 512; c0 = 0;   }
    else              { X = xkv; W = Wv; ldw = 512; c0 = 256; }

    const int ct   = t & 31;        // col-thread: cols ct*4 and 128+ct*4
    const int rt   = t >> 5;        // row-thread: rows rt*8..+7
    const int rs   = t & 63;        // x-staging row
    const int kx   = t >> 6;        // x-staging k-octet 0..3
    const int lane = t & 63;        // W-staging lane
    const int wv   = t >> 6;        // W-staging wave -> rows i*4+wv

    float4 accL[8], accH[8];
#pragma unroll
    for (int r = 0; r < 8; ++r) {
        accL[r] = make_float4(0.f, 0.f, 0.f, 0.f);
        accH[r] = make_float4(0.f, 0.f, 0.f, 0.f);
    }

    // prefetch registers
    float4 px0, px1, pw[8];
    {
        const float* xb = X + (long)(r0 + rs) * D_MODEL + 0 + kx * 8;
        px0 = *(const float4*)(xb);
        px1 = *(const float4*)(xb + 4);
#pragma unroll
        for (int i = 0; i < 8; ++i) {
            const int row = i * 4 + wv;
            pw[i] = *(const float4*)(W + (long)(0 + row) * ldw + c0 + lane * 4);
        }
    }

    for (int kc = 0; kc < D_MODEL; kc += KC) {
        __syncthreads();   // previous compute done -> safe to overwrite LDS
        // commit prefetched tile
        xt[(kx * 8 + 0) * MR + rs] = px0.x;
        xt[(kx * 8 + 1) * MR + rs] = px0.y;
        xt[(kx * 8 + 2) * MR + rs] = px0.z;
        xt[(kx * 8 + 3) * MR + rs] = px0.w;
        xt[(kx * 8 + 4) * MR + rs] = px1.x;
        xt[(kx * 8 + 5) * MR + rs] = px1.y;
        xt[(kx * 8 + 6) * MR + rs] = px1.z;
        xt[(kx * 8 + 7) * MR + rs] = px1.w;
#pragma unroll
        for (int i = 0; i < 8; ++i)
            *(float4*)(wt + (i * 4 + wv) * NC + lane * 4) = pw[i];
        __syncthreads();

        // issue next chunk's prefetch (lands behind ~4K cycles of FMA)
        const int kn = kc + KC;
        if (kn < D_MODEL) {
            const float* xb = X + (long)(r0 + rs) * D_MODEL + kn + kx * 8;
            px0 = *(const float4*)(xb);
            px1 = *(const float4*)(xb + 4);
#pragma unroll
            for (int i = 0; i < 8; ++i) {
                const int row = i * 4 + wv;
                pw[i] = *(const float4*)(W + (long)(kn + row) * ldw + c0 + lane * 4);
            }
        }

        // compute: 8x8 split-col register block, 64 FMA per k
#pragma unroll 2
        for (int k = 0; k < KC; ++k) {
            const float4 w0 = *(const float4*)(wt + k * NC + ct * 4);
            const float4 w1 = *(const float4*)(wt + k * NC + 128 + ct * 4);
            const float4 x0 = *(const float4*)(xt + k * MR + rt * 8);
            const float4 x1 = *(const float4*)(xt + k * MR + rt * 8 + 4);
            const float xr[8] = {x0.x, x0.y, x0.z, x0.w, x1.x, x1.y, x1.z, x1.w};
#pragma unroll
            for (int r = 0; r < 8; ++r) {
                accL[r].x = fmaf(xr[r], w0.x, accL[r].x);
                accL[r].y = fmaf(xr[r], w0.y, accL[r].y);
                accL[r].z = fmaf(xr[r], w0.z, accL[r].z);
                accL[r].w = fmaf(xr[r], w0.w, accL[r].w);
                accH[r].x = fmaf(xr[r], w1.x, accH[r].x);
                accH[r].y = fmaf(xr[r], w1.y, accH[r].y);
                accH[r].z = fmaf(xr[r], w1.z, accH[r].z);
                accH[r].w = fmaf(xr[r], w1.w, accH[r].w);
            }
        }
    }

    // epilogue: head-major scatter
    const int b  = r0 >> 9;
    const int sb = (r0 & 511) + rt * 8;
    if (bj <= 1) {
        float* dst = (bj == 0) ? Q2 : K2;
        const long hlo = ((long)b * HEAD + ct) * SEQ;        // col ct*4   -> head ct
        const long hhi = ((long)b * HEAD + 32 + ct) * SEQ;   // col 128+.. -> head 32+ct
#pragma unroll
        for (int r = 0; r < 8; ++r) {
            *(float4*)(dst + (hlo + sb + r) * 4) = accL[r];
            *(float4*)(dst + (hhi + sb + r) * 4) = accH[r];
        }
    } else {
        const int clo = c0 + ct * 4;
        const int chi = clo + 128;
        const long vlo = ((long)b * HEAD + (clo >> 3)) * SEQ;
        const long vhi = ((long)b * HEAD + (chi >> 3)) * SEQ;
        const int off = (ct & 1) * 4;
#pragma unroll
        for (int r = 0; r < 8; ++r) {
            *(float4*)(V2 + (vlo + sb + r) * 8 + off) = accL[r];
            *(float4*)(V2 + (vhi + sb + r) * 8 + off) = accH[r];
        }
    }
}

// ---------------------------------------------------------------------------
// Attention: one block per (b,h); 128 threads; 4 queries/thread (q=4t..4t+3)
// so each K/V LDS b128 serves 256 (q,s) pairs. Online softmax.
// Causal quirk: masked (s>q) scores are exactly 0 and participate; in-loop
// remainder predicates q0..q2 to 0; s>q3 handled as a shared lump
// exp(-M)*(count, suffixSumV). m0..m2 >= 0 from in-loop zeros; only m3 clamps.
// ---------------------------------------------------------------------------
template <int CAUSAL>
__global__ __launch_bounds__(128) void attn_kernel(
    const float* __restrict__ Q2, const float* __restrict__ K2,
    const float* __restrict__ V2, float* __restrict__ O)
{
    extern __shared__ float smem[];
    float* Kl = smem;                 // SEQ*DK = 2048 floats
    float* Vl = smem + SEQ * DK;      // SEQ*DV = 4096 floats
    float* cs = Vl + SEQ * DV;        // 33*DV  =  264 floats (causal only)

    const int t = threadIdx.x;
    const int bh = blockIdx.x;
    const int b = bh >> 6;
    const int h = bh & 63;

    const float4* Ks = (const float4*)(K2 + (long)bh * SEQ * DK);
#pragma unroll
    for (int i = 0; i < 4; ++i) ((float4*)Kl)[t + i * 128] = Ks[t + i * 128];
    const float4* Vs = (const float4*)(V2 + (long)bh * SEQ * DV);
#pragma unroll
    for (int i = 0; i < 8; ++i) ((float4*)Vl)[t + i * 128] = Vs[t + i * 128];
    __syncthreads();

    if (CAUSAL) {
#pragma unroll
        for (int w = t; w < 256; w += 128) {
            const int ch = w >> 3, d = w & 7;
            float s16 = 0.f;
#pragma unroll
            for (int i = 0; i < 16; ++i) s16 += Vl[(ch * 16 + i) * 8 + d];
            cs[ch * 8 + d] = s16;
        }
        __syncthreads();
        if (t < 8) {
            cs[256 + t] = 0.f;
            float run = 0.f;
            for (int c2 = 31; c2 >= 0; --c2) {
                run += cs[c2 * 8 + t];
                cs[c2 * 8 + t] = run;   // inclusive suffix of chunk c2
            }
        }
        __syncthreads();
    }

    const int qb = 4 * t;
    float qf[4][4];
#pragma unroll
    for (int j = 0; j < 4; ++j) {
        const float4 qv = *(const float4*)(Q2 + ((long)bh * SEQ + qb + j) * 4);
        qf[j][0] = qv.x * 0.5f; qf[j][1] = qv.y * 0.5f;   // fold 1/sqrt(DK)
        qf[j][2] = qv.z * 0.5f; qf[j][3] = qv.w * 0.5f;
    }

    float m[4], l[4], A[4][8];
#pragma unroll
    for (int j = 0; j < 4; ++j) {
        m[j] = -INFINITY; l[j] = 0.f;
#pragma unroll
        for (int d = 0; d < 8; ++d) A[j][d] = 0.f;
    }

    const int full_end = CAUSAL ? (qb + 1) : SEQ;   // groups fully unmasked

    int s0 = 0;
    for (; s0 + 8 <= full_end; s0 += 8) {
        float sc[4][8];
#pragma unroll
        for (int i = 0; i < 8; ++i) {
            const float4 k4 = *(const float4*)(Kl + (s0 + i) * 4);
#pragma unroll
            for (int j = 0; j < 4; ++j)
                sc[j][i] = fmaf(qf[j][0], k4.x, fmaf(qf[j][1], k4.y,
                           fmaf(qf[j][2], k4.z, qf[j][3] * k4.w)));
        }
#pragma unroll
        for (int j = 0; j < 4; ++j) {
            float gm = fmaxf(fmaxf(fmaxf(sc[j][0], sc[j][1]), fmaxf(sc[j][2], sc[j][3])),
                             fmaxf(fmaxf(sc[j][4], sc[j][5]), fmaxf(sc[j][6], sc[j][7])));
            if (gm > m[j]) {
                const float r = __expf(m[j] - gm);
                l[j] *= r;
#pragma unroll
                for (int d = 0; d < 8; ++d) A[j][d] *= r;
                m[j] = gm;
            }
        }
#pragma unroll
        for (int i = 0; i < 8; ++i) {
            const float4 v0 = *(const float4*)(Vl + (s0 + i) * 8);
            const float4 v1 = *(const float4*)(Vl + (s0 + i) * 8 + 4);
#pragma unroll
            for (int j = 0; j < 4; ++j) {
                const float p = __expf(sc[j][i] - m[j]);
                l[j] += p;
                A[j][0] = fmaf(p, v0.x, A[j][0]); A[j][1] = fmaf(p, v0.y, A[j][1]);
                A[j][2] = fmaf(p, v0.z, A[j][2]); A[j][3] = fmaf(p, v0.w, A[j][3]);
                A[j][4] = fmaf(p, v1.x, A[j][4]); A[j][5] = fmaf(p, v1.y, A[j][5]);
                A[j][6] = fmaf(p, v1.z, A[j][6]); A[j][7] = fmaf(p, v1.w, A[j][7]);
            }
        }
    }

    if (CAUSAL) {
        const int q3 = qb + 3;
        for (int s = s0; s <= q3; ++s) {          // short predicated remainder
            const float4 k4 = *(const float4*)(Kl + s * 4);
            float scj[4];
#pragma unroll
            for (int j = 0; j < 4; ++j)
                scj[j] = fmaf(qf[j][0], k4.x, fmaf(qf[j][1], k4.y,
                         fmaf(qf[j][2], k4.z, qf[j][3] * k4.w)));
            scj[0] = (s <= qb)     ? scj[0] : 0.f;  // mult-mask quirk: exact 0
            scj[1] = (s <= qb + 1) ? scj[1] : 0.f;
            scj[2] = (s <= qb + 2) ? scj[2] : 0.f;
            const float4 v0 = *(const float4*)(Vl + s * 8);
            const float4 v1 = *(const float4*)(Vl + s * 8 + 4);
#pragma unroll
            for (int j = 0; j < 4; ++j) {
                if (scj[j] > m[j]) {
                    const float r = __expf(m[j] - scj[j]);
                    l[j] *= r;
#pragma unroll
                    for (int d = 0; d < 8; ++d) A[j][d] *= r;
                    m[j] = scj[j];
                }
                const float p = __expf(scj[j] - m[j]);
                l[j] += p;
                A[j][0] = fmaf(p, v0.x, A[j][0]); A[j][1] = fmaf(p, v0.y, A[j][1]);
                A[j][2] = fmaf(p, v0.z, A[j][2]); A[j][3] = fmaf(p, v0.w, A[j][3]);
                A[j][4] = fmaf(p, v1.x, A[j][4]); A[j][5] = fmaf(p, v1.y, A[j][5]);
                A[j][6] = fmaf(p, v1.z, A[j][6]); A[j][7] = fmaf(p, v1.w, A[j][7]);
            }
        }

        const int n = SEQ - 1 - q3;               // masked count beyond q3
        if (n > 0) {
            const int nq = q3 + 1;
            const int cq2 = nq >> 4;
            float sv[8];
#pragma unroll
            for (int d = 0; d < 8; ++d) sv[d] = cs[(cq2 + 1) * 8 + d];
            for (int s = nq; s < (cq2 + 1) * 16; ++s) {
                const float4 v0 = *(const float4*)(Vl + s * 8);
                const float4 v1 = *(const float4*)(Vl + s * 8 + 4);
                sv[0] += v0.x; sv[1] += v0.y; sv[2] += v0.z; sv[3] += v0.w;
                sv[4] += v1.x; sv[5] += v1.y; sv[6] += v1.z; sv[7] += v1.w;
            }
            // j=0..2: m[j] >= 0 (in-loop zeros seen) -> no rescale needed
#pragma unroll
            for (int j = 0; j < 3; ++j) {
                const float pm = __expf(-m[j]);
                l[j] += pm * (float)n;
#pragma unroll
                for (int d = 0; d < 8; ++d) A[j][d] = fmaf(pm, sv[d], A[j][d]);
            }
            const float M3  = fmaxf(m[3], 0.f);
            const float r3  = __expf(m[3] - M3);
            const float pm3 = __expf(-M3);
            l[3] = l[3] * r3 + pm3 * (float)n;
#pragma unroll
            for (int d = 0; d < 8; ++d) A[3][d] = A[3][d] * r3 + pm3 * sv[d];
        }
    }

#pragma unroll
    for (int j = 0; j < 4; ++j) {
        const float inv = 1.0f / l[j];
        const long ob = ((long)b * SEQ + qb + j) * 512 + h * DV;
        *(float4*)(O + ob)     = make_float4(A[j][0]*inv, A[j][1]*inv, A[j][2]*inv, A[j][3]*inv);
        *(float4*)(O + ob + 4) = make_float4(A[j][4]*inv, A[j][5]*inv, A[j][6]*inv, A[j][7]*inv);
    }
}

// ---------------------------------------------------------------------------
// Fused residual + LayerNorm + MLP (512 -> 10 -> 512).
// One WAVE per row; 256 threads = 4 rows/block. (unchanged)
// ---------------------------------------------------------------------------
__global__ __launch_bounds__(256) void ln_mlp_kernel(
    const float* __restrict__ x, const float* __restrict__ fx,
    const float* __restrict__ g, const float* __restrict__ beta,
    const float* __restrict__ w1, const float* __restrict__ b1,
    const float* __restrict__ w2, const float* __restrict__ b2,
    float* __restrict__ out)
{
    const int t = threadIdx.x;
    const int lane = t & 63;
    const int row = blockIdx.x * 4 + (t >> 6);
    const long base = (long)row * D_MODEL;
    const int e0 = lane * 8;

    const float4 xa = *(const float4*)(x + base + e0);
    const float4 xb = *(const float4*)(x + base + e0 + 4);
    const float4 fa = *(const float4*)(fx + base + e0);
    const float4 fb = *(const float4*)(fx + base + e0 + 4);
    float z[8] = {xa.x+fa.x, xa.y+fa.y, xa.z+fa.z, xa.w+fa.w,
                  xb.x+fb.x, xb.y+fb.y, xb.z+fb.z, xb.w+fb.w};

    float sum = 0.f;
#pragma unroll
    for (int j = 0; j < 8; ++j) sum += z[j];
#pragma unroll
    for (int o = 32; o > 0; o >>= 1) sum += __shfl_xor(sum, o);
    float mu = sum * (1.0f / 512.0f);

    float d[8], ss = 0.f;
#pragma unroll
    for (int j = 0; j < 8; ++j) { d[j] = z[j] - mu; ss += d[j] * d[j]; }
#pragma unroll
    for (int o = 32; o > 0; o >>= 1) ss += __shfl_xor(ss, o);
    float rs = rsqrtf(ss * (1.0f / 512.0f) + 1e-5f);

    const float4 ga = *(const float4*)(g + e0);
    const float4 gb = *(const float4*)(g + e0 + 4);
    const float4 ba = *(const float4*)(beta + e0);
    const float4 bb = *(const float4*)(beta + e0 + 4);
    const float gg[8] = {ga.x,ga.y,ga.z,ga.w,gb.x,gb.y,gb.z,gb.w};
    const float bt[8] = {ba.x,ba.y,ba.z,ba.w,bb.x,bb.y,bb.z,bb.w};
    float y[8];
#pragma unroll
    for (int j = 0; j < 8; ++j) y[j] = d[j] * rs * gg[j] + bt[j];

    float part[HIDD];
#pragma unroll
    for (int i = 0; i < HIDD; ++i) {
        const float4 wa = *(const float4*)(w1 + i * 512 + e0);
        const float4 wb = *(const float4*)(w1 + i * 512 + e0 + 4);
        part[i] = y[0]*wa.x + y[1]*wa.y + y[2]*wa.z + y[3]*wa.w
                + y[4]*wb.x + y[5]*wb.y + y[6]*wb.z + y[7]*wb.w;
    }
#pragma unroll
    for (int i = 0; i < HIDD; ++i)
#pragma unroll
        for (int o = 32; o > 0; o >>= 1) part[i] += __shfl_xor(part[i], o);

    float hv[HIDD];
#pragma unroll
    for (int i = 0; i < HIDD; ++i) hv[i] = fmaxf(part[i] + b1[i], 0.f);

    float o8[8];
#pragma unroll
    for (int j = 0; j < 8; ++j) o8[j] = b2[e0 + j];
#pragma unroll
    for (int i = 0; i < HIDD; ++i)
#pragma unroll
        for (int j = 0; j < 8; ++j)
            o8[j] = fmaf(hv[i], w2[(long)(e0 + j) * 10 + i], o8[j]);

    *(float4*)(out + base + e0)     = make_float4(o8[0], o8[1], o8[2], o8[3]);
    *(float4*)(out + base + e0 + 4) = make_float4(o8[4], o8[5], o8[6], o8[7]);
}

extern "C" void kernel_launch(void* const* d_in, const int* in_sizes, int n_in,
                              void* d_out, int out_size, void* d_ws, size_t ws_size,
                              hipStream_t stream) {
    (void)in_sizes; (void)n_in; (void)out_size; (void)ws_size;
    const float* x    = (const float*)d_in[0];
    const float* xenc = (const float*)d_in[1];
    const float* Wq   = (const float*)d_in[2];
    const float* Wk   = (const float*)d_in[3];
    const float* Wv   = (const float*)d_in[4];
    const float* ln_g = (const float*)d_in[5];
    const float* ln_b = (const float*)d_in[6];
    const float* w1   = (const float*)d_in[7];
    const float* b1   = (const float*)d_in[8];
    const float* w2   = (const float*)d_in[9];
    const float* b2   = (const float*)d_in[10];
    float* out = (float*)d_out;

    float* ws = (float*)d_ws;
    float* Q2 = ws;                   // [b][h][s][4]
    float* K2 = Q2 + 1048576;         // [b][h][s][4]
    float* V2 = K2 + 1048576;         // [b][h][s][8]
    float* A  = V2 + 2097152;         // row-major [b][s][512]

    const int nrows = BATCH * SEQ;    // 4096
    const size_t lds_cross  = (size_t)(SEQ * DK + SEQ * DV) * 4;          // 24576
    const size_t lds_causal = lds_cross + (size_t)(33 * DV) * 4;          // 25632
    const int proj_grid = (nrows / MR) * 4;                               // 256

    // Stage 1: self-attention (causal multiplicative mask)
    proj_kernel<<<dim3(proj_grid), 256, 0, stream>>>(x, x, Wq, Wk, Wv, Q2, K2, V2);
    attn_kernel<1><<<dim3(BATCH * HEAD), 128, lds_causal, stream>>>(Q2, K2, V2, A);

    // Stage 2: cross-attention (same weights — faithful quirk)
    proj_kernel<<<dim3(proj_grid), 256, 0, stream>>>(A, xenc, Wq, Wk, Wv, Q2, K2, V2);
    attn_kernel<0><<<dim3(BATCH * HEAD), 128, lds_cross, stream>>>(Q2, K2, V2, A);

    // Stage 3: residual(x) + LayerNorm + MLP
    ln_mlp_kernel<<<dim3(nrows / 4), 256, 0, stream>>>(x, A, ln_g, ln_b,
                                                       w1, b1, w2, b2, out);
}

// Round 8
// 349.415 us; speedup vs baseline: 1.3551x; 1.3551x over previous
//
#include <hip/hip_runtime.h>
#include <math.h>

#define D_MODEL 512
#define BATCH 8
#define SEQ 512
#define HEAD 64
#define DK 4
#define DV 8
#define HIDD 10

// proj tiled-GEMM params
#define MR 64    // rows per block
#define KC 32    // k-chunk staged per barrier
#define NC 256   // cols per block

// ---------------------------------------------------------------------------
// Projection as tiled GEMM, k-SPLIT across blocks for TLP:
// [4096 x 512] @ [512 x 1024] -> head-major {Q|K|V} partials.
// SPLIT=1: grid = 64 row-blocks x 4 col-jobs x 2 k-halves = 512 blocks
//          (2+ blocks/CU); each writes its half-k partial to set a or b;
//          attention staging adds the two partials (deterministic).
// SPLIT=0: grid 256, full k, writes set a only (ws too small fallback).
// 256 threads; thread = rt (8 rows) x ct (cols {ct*4..+3, 128+ct*4..+3}).
// Split-pair cols -> W b128 reads are 16B-lane-stride = conflict-free.
// Per k: 2 W b128 + 2 x b128 (broadcast) feed 64 FMA.
// ---------------------------------------------------------------------------
template <int SPLIT>
__global__ __launch_bounds__(256) void proj_kernel(
    const float* __restrict__ xq, const float* __restrict__ xkv,
    const float* __restrict__ Wq, const float* __restrict__ Wk,
    const float* __restrict__ Wv,
    float* __restrict__ Qa, float* __restrict__ Ka, float* __restrict__ Va,
    float* __restrict__ Qb, float* __restrict__ Kb, float* __restrict__ Vb)
{
    __shared__ float xt[KC * MR];   // [k][r]  8 KB
    __shared__ float wt[KC * NC];   // [k][c] 32 KB

    const int t   = threadIdx.x;
    const int bid = blockIdx.x;
    const int ks  = SPLIT ? (bid & 1) : 0;
    const int bj  = SPLIT ? ((bid >> 1) & 3) : (bid & 3);
    const int br  = SPLIT ? (bid >> 3) : (bid >> 2);
    const int r0  = br * MR;
    const int kbase = ks * 256;
    const int kend  = kbase + (SPLIT ? 256 : 512);

    const float* X; const float* W; int ldw; int c0;
    if (bj == 0)      { X = xq;  W = Wq; ldw = 256; c0 = 0;   }
    else if (bj == 1) { X = xkv; W = Wk; ldw = 256; c0 = 0;   }
    else if (bj == 2) { X = xkv; W = Wv; ldw = 512; c0 = 0;   }
    else              { X = xkv; W = Wv; ldw = 512; c0 = 256; }

    float* Q2 = ks ? Qb : Qa;
    float* K2 = ks ? Kb : Ka;
    float* V2 = ks ? Vb : Va;

    const int ct   = t & 31;        // col-thread: cols ct*4 and 128+ct*4
    const int rt   = t >> 5;        // row-thread: rows rt*8..+7
    const int rs   = t & 63;        // x-staging row
    const int kx   = t >> 6;        // x-staging k-octet 0..3
    const int lane = t & 63;        // W-staging lane
    const int wv   = t >> 6;        // W-staging wave -> rows i*4+wv

    float4 accL[8], accH[8];
#pragma unroll
    for (int r = 0; r < 8; ++r) {
        accL[r] = make_float4(0.f, 0.f, 0.f, 0.f);
        accH[r] = make_float4(0.f, 0.f, 0.f, 0.f);
    }

    for (int kc = kbase; kc < kend; kc += KC) {
        // ---- stage x tile transposed [k][r] (2-way bank groups = free) ----
        {
            const float* xb = X + (long)(r0 + rs) * D_MODEL + kc + kx * 8;
            const float4 xa4 = *(const float4*)(xb);
            const float4 xb4 = *(const float4*)(xb + 4);
            xt[(kx * 8 + 0) * MR + rs] = xa4.x;
            xt[(kx * 8 + 1) * MR + rs] = xa4.y;
            xt[(kx * 8 + 2) * MR + rs] = xa4.z;
            xt[(kx * 8 + 3) * MR + rs] = xa4.w;
            xt[(kx * 8 + 4) * MR + rs] = xb4.x;
            xt[(kx * 8 + 5) * MR + rs] = xb4.y;
            xt[(kx * 8 + 6) * MR + rs] = xb4.z;
            xt[(kx * 8 + 7) * MR + rs] = xb4.w;
        }
        // ---- stage W tile: wave wv loads rows i*4+wv, 1 KB contiguous ----
#pragma unroll
        for (int i = 0; i < 8; ++i) {
            const int row = i * 4 + wv;
            *(float4*)(wt + row * NC + lane * 4) =
                *(const float4*)(W + (long)(kc + row) * ldw + c0 + lane * 4);
        }
        __syncthreads();

        // ---- compute: 8x8 split-col register block, 64 FMA per k ----
#pragma unroll 2
        for (int k = 0; k < KC; ++k) {
            const float4 w0 = *(const float4*)(wt + k * NC + ct * 4);
            const float4 w1 = *(const float4*)(wt + k * NC + 128 + ct * 4);
            const float4 x0 = *(const float4*)(xt + k * MR + rt * 8);
            const float4 x1 = *(const float4*)(xt + k * MR + rt * 8 + 4);
            const float xr[8] = {x0.x, x0.y, x0.z, x0.w, x1.x, x1.y, x1.z, x1.w};
#pragma unroll
            for (int r = 0; r < 8; ++r) {
                accL[r].x = fmaf(xr[r], w0.x, accL[r].x);
                accL[r].y = fmaf(xr[r], w0.y, accL[r].y);
                accL[r].z = fmaf(xr[r], w0.z, accL[r].z);
                accL[r].w = fmaf(xr[r], w0.w, accL[r].w);
                accH[r].x = fmaf(xr[r], w1.x, accH[r].x);
                accH[r].y = fmaf(xr[r], w1.y, accH[r].y);
                accH[r].z = fmaf(xr[r], w1.z, accH[r].z);
                accH[r].w = fmaf(xr[r], w1.w, accH[r].w);
            }
        }
        __syncthreads();
    }

    // ---- epilogue: head-major scatter ----
    const int b  = r0 >> 9;
    const int sb = (r0 & 511) + rt * 8;
    if (bj <= 1) {
        float* dst = (bj == 0) ? Q2 : K2;
        const long hlo = ((long)b * HEAD + ct) * SEQ;        // col ct*4   -> head ct
        const long hhi = ((long)b * HEAD + 32 + ct) * SEQ;   // col 128+.. -> head 32+ct
#pragma unroll
        for (int r = 0; r < 8; ++r) {
            *(float4*)(dst + (hlo + sb + r) * 4) = accL[r];
            *(float4*)(dst + (hhi + sb + r) * 4) = accH[r];
        }
    } else {
        const int clo = c0 + ct * 4;
        const int chi = clo + 128;
        const long vlo = ((long)b * HEAD + (clo >> 3)) * SEQ;
        const long vhi = ((long)b * HEAD + (chi >> 3)) * SEQ;
        const int off = (ct & 1) * 4;
#pragma unroll
        for (int r = 0; r < 8; ++r) {
            *(float4*)(V2 + (vlo + sb + r) * 8 + off) = accL[r];
            *(float4*)(V2 + (vhi + sb + r) * 8 + off) = accH[r];
        }
    }
}

// ---------------------------------------------------------------------------
// Attention: one block per (b,h,q-half); 128 threads; 2 queries/thread
// (q = qh*256 + 2t, +1). 1024 blocks x 2 waves -> 4 blocks/CU = 8 waves/CU
// (fixes R7's 8% occupancy) while keeping halved LDS traffic.
// ADD2=1: K/V/Q inputs are two k-split partials, summed during staging.
// Causal quirk: masked (s>q) scores are exactly 0 and participate; remainder
// predicates q0; s>q1 handled as lump exp(-M)*(count, suffixSumV).
// ---------------------------------------------------------------------------
template <int CAUSAL, int ADD2>
__global__ __launch_bounds__(128) void attn_kernel(
    const float* __restrict__ Qa, const float* __restrict__ Ka,
    const float* __restrict__ Va, const float* __restrict__ Qb,
    const float* __restrict__ Kb, const float* __restrict__ Vb,
    float* __restrict__ O)
{
    extern __shared__ float smem[];
    float* Kl = smem;                 // SEQ*DK = 2048 floats
    float* Vl = smem + SEQ * DK;      // SEQ*DV = 4096 floats
    float* cs = Vl + SEQ * DV;        // 33*DV  =  264 floats (causal only)

    const int t  = threadIdx.x;
    const int qh = blockIdx.x & 1;
    const int bh = blockIdx.x >> 1;
    const int b  = bh >> 6;
    const int h  = bh & 63;

    const float4* Ksa = (const float4*)(Ka + (long)bh * SEQ * DK);
    const float4* Ksb = (const float4*)(Kb + (long)bh * SEQ * DK);
#pragma unroll
    for (int i = 0; i < 4; ++i) {
        float4 v = Ksa[t + i * 128];
        if (ADD2) {
            const float4 w = Ksb[t + i * 128];
            v.x += w.x; v.y += w.y; v.z += w.z; v.w += w.w;
        }
        ((float4*)Kl)[t + i * 128] = v;
    }
    const float4* Vsa = (const float4*)(Va + (long)bh * SEQ * DV);
    const float4* Vsb = (const float4*)(Vb + (long)bh * SEQ * DV);
#pragma unroll
    for (int i = 0; i < 8; ++i) {
        float4 v = Vsa[t + i * 128];
        if (ADD2) {
            const float4 w = Vsb[t + i * 128];
            v.x += w.x; v.y += w.y; v.z += w.z; v.w += w.w;
        }
        ((float4*)Vl)[t + i * 128] = v;
    }
    __syncthreads();

    if (CAUSAL) {
#pragma unroll
        for (int w = t; w < 256; w += 128) {
            const int ch = w >> 3, d = w & 7;
            float s16 = 0.f;
#pragma unroll
            for (int i = 0; i < 16; ++i) s16 += Vl[(ch * 16 + i) * 8 + d];
            cs[ch * 8 + d] = s16;
        }
        __syncthreads();
        if (t < 8) {
            cs[256 + t] = 0.f;
            float run = 0.f;
            for (int c2 = 31; c2 >= 0; --c2) {
                run += cs[c2 * 8 + t];
                cs[c2 * 8 + t] = run;   // inclusive suffix of chunk c2
            }
        }
        __syncthreads();
    }

    const int q0 = qh * 256 + 2 * t, q1 = q0 + 1;
    float4 qva = *(const float4*)(Qa + ((long)bh * SEQ + q0) * 4);
    float4 qvb = *(const float4*)(Qa + ((long)bh * SEQ + q1) * 4);
    if (ADD2) {
        const float4 wa = *(const float4*)(Qb + ((long)bh * SEQ + q0) * 4);
        const float4 wb = *(const float4*)(Qb + ((long)bh * SEQ + q1) * 4);
        qva.x += wa.x; qva.y += wa.y; qva.z += wa.z; qva.w += wa.w;
        qvb.x += wb.x; qvb.y += wb.y; qvb.z += wb.z; qvb.w += wb.w;
    }
    const float qa0 = qva.x*0.5f, qa1 = qva.y*0.5f, qa2 = qva.z*0.5f, qa3 = qva.w*0.5f;
    const float qb0 = qvb.x*0.5f, qb1 = qvb.y*0.5f, qb2 = qvb.z*0.5f, qb3 = qvb.w*0.5f;

    float m0 = -INFINITY, l0 = 0.f, m1 = -INFINITY, l1 = 0.f;
    float A0[8], A1[8];
#pragma unroll
    for (int d = 0; d < 8; ++d) { A0[d] = 0.f; A1[d] = 0.f; }

    const int full_end = CAUSAL ? (q0 + 1) : SEQ;   // groups with no masking

    int s0 = 0;
    for (; s0 + 8 <= full_end; s0 += 8) {
        float sa[8], sb[8];
#pragma unroll
        for (int i = 0; i < 8; ++i) {
            const float4 k4 = *(const float4*)(Kl + (s0 + i) * 4);
            sa[i] = fmaf(qa0, k4.x, fmaf(qa1, k4.y, fmaf(qa2, k4.z, qa3 * k4.w)));
            sb[i] = fmaf(qb0, k4.x, fmaf(qb1, k4.y, fmaf(qb2, k4.z, qb3 * k4.w)));
        }
        const float ga = fmaxf(fmaxf(fmaxf(sa[0], sa[1]), fmaxf(sa[2], sa[3])),
                               fmaxf(fmaxf(sa[4], sa[5]), fmaxf(sa[6], sa[7])));
        const float gb = fmaxf(fmaxf(fmaxf(sb[0], sb[1]), fmaxf(sb[2], sb[3])),
                               fmaxf(fmaxf(sb[4], sb[5]), fmaxf(sb[6], sb[7])));
        if (ga > m0) {
            const float r = __expf(m0 - ga);
            l0 *= r;
#pragma unroll
            for (int d = 0; d < 8; ++d) A0[d] *= r;
            m0 = ga;
        }
        if (gb > m1) {
            const float r = __expf(m1 - gb);
            l1 *= r;
#pragma unroll
            for (int d = 0; d < 8; ++d) A1[d] *= r;
            m1 = gb;
        }
#pragma unroll
        for (int i = 0; i < 8; ++i) {
            const float p0 = __expf(sa[i] - m0);
            const float p1 = __expf(sb[i] - m1);
            l0 += p0; l1 += p1;
            const float4 v0 = *(const float4*)(Vl + (s0 + i) * 8);
            const float4 v1 = *(const float4*)(Vl + (s0 + i) * 8 + 4);
            A0[0] = fmaf(p0, v0.x, A0[0]); A0[1] = fmaf(p0, v0.y, A0[1]);
            A0[2] = fmaf(p0, v0.z, A0[2]); A0[3] = fmaf(p0, v0.w, A0[3]);
            A0[4] = fmaf(p0, v1.x, A0[4]); A0[5] = fmaf(p0, v1.y, A0[5]);
            A0[6] = fmaf(p0, v1.z, A0[6]); A0[7] = fmaf(p0, v1.w, A0[7]);
            A1[0] = fmaf(p1, v0.x, A1[0]); A1[1] = fmaf(p1, v0.y, A1[1]);
            A1[2] = fmaf(p1, v0.z, A1[2]); A1[3] = fmaf(p1, v0.w, A1[3]);
            A1[4] = fmaf(p1, v1.x, A1[4]); A1[5] = fmaf(p1, v1.y, A1[5]);
            A1[6] = fmaf(p1, v1.z, A1[6]); A1[7] = fmaf(p1, v1.w, A1[7]);
        }
    }

    if (CAUSAL) {
        for (int s = s0; s <= q1; ++s) {        // remainder: covers s=q0+1
            const float4 k4 = *(const float4*)(Kl + s * 4);
            float sa = fmaf(qa0, k4.x, fmaf(qa1, k4.y, fmaf(qa2, k4.z, qa3 * k4.w)));
            float sb = fmaf(qb0, k4.x, fmaf(qb1, k4.y, fmaf(qb2, k4.z, qb3 * k4.w)));
            sa = (s <= q0) ? sa : 0.f;          // mult-mask quirk: exact 0
            if (sa > m0) {
                const float r = __expf(m0 - sa);
                l0 *= r;
#pragma unroll
                for (int d = 0; d < 8; ++d) A0[d] *= r;
                m0 = sa;
            }
            if (sb > m1) {
                const float r = __expf(m1 - sb);
                l1 *= r;
#pragma unroll
                for (int d = 0; d < 8; ++d) A1[d] *= r;
                m1 = sb;
            }
            const float p0 = __expf(sa - m0);
            const float p1 = __expf(sb - m1);
            l0 += p0; l1 += p1;
            const float4 v0 = *(const float4*)(Vl + s * 8);
            const float4 v1 = *(const float4*)(Vl + s * 8 + 4);
            A0[0] = fmaf(p0, v0.x, A0[0]); A0[1] = fmaf(p0, v0.y, A0[1]);
            A0[2] = fmaf(p0, v0.z, A0[2]); A0[3] = fmaf(p0, v0.w, A0[3]);
            A0[4] = fmaf(p0, v1.x, A0[4]); A0[5] = fmaf(p0, v1.y, A0[5]);
            A0[6] = fmaf(p0, v1.z, A0[6]); A0[7] = fmaf(p0, v1.w, A0[7]);
            A1[0] = fmaf(p1, v0.x, A1[0]); A1[1] = fmaf(p1, v0.y, A1[1]);
            A1[2] = fmaf(p1, v0.z, A1[2]); A1[3] = fmaf(p1, v0.w, A1[3]);
            A1[4] = fmaf(p1, v1.x, A1[4]); A1[5] = fmaf(p1, v1.y, A1[5]);
            A1[6] = fmaf(p1, v1.z, A1[6]); A1[7] = fmaf(p1, v1.w, A1[7]);
        }

        const int n = SEQ - 1 - q1;             // masked zeros beyond q1
        if (n > 0) {
            const int nq  = q1 + 1;
            const int cq2 = nq >> 4;
            float sv[8];
#pragma unroll
            for (int d = 0; d < 8; ++d) sv[d] = cs[(cq2 + 1) * 8 + d];
            for (int s = nq; s < (cq2 + 1) * 16; ++s) {
                const float4 v0 = *(const float4*)(Vl + s * 8);
                const float4 v1 = *(const float4*)(Vl + s * 8 + 4);
                sv[0] += v0.x; sv[1] += v0.y; sv[2] += v0.z; sv[3] += v0.w;
                sv[4] += v1.x; sv[5] += v1.y; sv[6] += v1.z; sv[7] += v1.w;
            }
            // q0 saw an in-loop zero -> m0 >= 0 already
            const float pm0 = __expf(-m0);
            l0 += pm0 * (float)n;
#pragma unroll
            for (int d = 0; d < 8; ++d) A0[d] = fmaf(pm0, sv[d], A0[d]);

            const float M1  = fmaxf(m1, 0.f);
            const float r1  = __expf(m1 - M1);
            const float pm1 = __expf(-M1);
            l1 = l1 * r1 + pm1 * (float)n;
#pragma unroll
            for (int d = 0; d < 8; ++d) A1[d] = A1[d] * r1 + pm1 * sv[d];
        }
    }

    const float i0 = 1.0f / l0, i1 = 1.0f / l1;
    const long ob0 = ((long)b * SEQ + q0) * 512 + h * DV;
    const long ob1 = ((long)b * SEQ + q1) * 512 + h * DV;
    *(float4*)(O + ob0)     = make_float4(A0[0]*i0, A0[1]*i0, A0[2]*i0, A0[3]*i0);
    *(float4*)(O + ob0 + 4) = make_float4(A0[4]*i0, A0[5]*i0, A0[6]*i0, A0[7]*i0);
    *(float4*)(O + ob1)     = make_float4(A1[0]*i1, A1[1]*i1, A1[2]*i1, A1[3]*i1);
    *(float4*)(O + ob1 + 4) = make_float4(A1[4]*i1, A1[5]*i1, A1[6]*i1, A1[7]*i1);
}

// ---------------------------------------------------------------------------
// Fused residual + LayerNorm + MLP (512 -> 10 -> 512).
// One WAVE per row; 256 threads = 4 rows/block. (unchanged)
// ---------------------------------------------------------------------------
__global__ __launch_bounds__(256) void ln_mlp_kernel(
    const float* __restrict__ x, const float* __restrict__ fx,
    const float* __restrict__ g, const float* __restrict__ beta,
    const float* __restrict__ w1, const float* __restrict__ b1,
    const float* __restrict__ w2, const float* __restrict__ b2,
    float* __restrict__ out)
{
    const int t = threadIdx.x;
    const int lane = t & 63;
    const int row = blockIdx.x * 4 + (t >> 6);
    const long base = (long)row * D_MODEL;
    const int e0 = lane * 8;

    const float4 xa = *(const float4*)(x + base + e0);
    const float4 xb = *(const float4*)(x + base + e0 + 4);
    const float4 fa = *(const float4*)(fx + base + e0);
    const float4 fb = *(const float4*)(fx + base + e0 + 4);
    float z[8] = {xa.x+fa.x, xa.y+fa.y, xa.z+fa.z, xa.w+fa.w,
                  xb.x+fb.x, xb.y+fb.y, xb.z+fb.z, xb.w+fb.w};

    float sum = 0.f;
#pragma unroll
    for (int j = 0; j < 8; ++j) sum += z[j];
#pragma unroll
    for (int o = 32; o > 0; o >>= 1) sum += __shfl_xor(sum, o);
    float mu = sum * (1.0f / 512.0f);

    float d[8], ss = 0.f;
#pragma unroll
    for (int j = 0; j < 8; ++j) { d[j] = z[j] - mu; ss += d[j] * d[j]; }
#pragma unroll
    for (int o = 32; o > 0; o >>= 1) ss += __shfl_xor(ss, o);
    float rs = rsqrtf(ss * (1.0f / 512.0f) + 1e-5f);

    const float4 ga = *(const float4*)(g + e0);
    const float4 gb = *(const float4*)(g + e0 + 4);
    const float4 ba = *(const float4*)(beta + e0);
    const float4 bb = *(const float4*)(beta + e0 + 4);
    const float gg[8] = {ga.x,ga.y,ga.z,ga.w,gb.x,gb.y,gb.z,gb.w};
    const float bt[8] = {ba.x,ba.y,ba.z,ba.w,bb.x,bb.y,bb.z,bb.w};
    float y[8];
#pragma unroll
    for (int j = 0; j < 8; ++j) y[j] = d[j] * rs * gg[j] + bt[j];

    float part[HIDD];
#pragma unroll
    for (int i = 0; i < HIDD; ++i) {
        const float4 wa = *(const float4*)(w1 + i * 512 + e0);
        const float4 wb = *(const float4*)(w1 + i * 512 + e0 + 4);
        part[i] = y[0]*wa.x + y[1]*wa.y + y[2]*wa.z + y[3]*wa.w
                + y[4]*wb.x + y[5]*wb.y + y[6]*wb.z + y[7]*wb.w;
    }
#pragma unroll
    for (int i = 0; i < HIDD; ++i)
#pragma unroll
        for (int o = 32; o > 0; o >>= 1) part[i] += __shfl_xor(part[i], o);

    float hv[HIDD];
#pragma unroll
    for (int i = 0; i < HIDD; ++i) hv[i] = fmaxf(part[i] + b1[i], 0.f);

    float o8[8];
#pragma unroll
    for (int j = 0; j < 8; ++j) o8[j] = b2[e0 + j];
#pragma unroll
    for (int i = 0; i < HIDD; ++i)
#pragma unroll
        for (int j = 0; j < 8; ++j)
            o8[j] = fmaf(hv[i], w2[(long)(e0 + j) * 10 + i], o8[j]);

    *(float4*)(out + base + e0)     = make_float4(o8[0], o8[1], o8[2], o8[3]);
    *(float4*)(out + base + e0 + 4) = make_float4(o8[4], o8[5], o8[6], o8[7]);
}

extern "C" void kernel_launch(void* const* d_in, const int* in_sizes, int n_in,
                              void* d_out, int out_size, void* d_ws, size_t ws_size,
                              hipStream_t stream) {
    (void)in_sizes; (void)n_in; (void)out_size;
    const float* x    = (const float*)d_in[0];
    const float* xenc = (const float*)d_in[1];
    const float* Wq   = (const float*)d_in[2];
    const float* Wk   = (const float*)d_in[3];
    const float* Wv   = (const float*)d_in[4];
    const float* ln_g = (const float*)d_in[5];
    const float* ln_b = (const float*)d_in[6];
    const float* w1   = (const float*)d_in[7];
    const float* b1   = (const float*)d_in[8];
    const float* w2   = (const float*)d_in[9];
    const float* b2   = (const float*)d_in[10];
    float* out = (float*)d_out;

    float* ws = (float*)d_ws;
    // set a: Qa[1M] Ka[1M] Va[2M]; set b (split only): Qb Kb Vb; then A[2M]
    float* Qa = ws;
    float* Ka = Qa + 1048576;
    float* Va = Ka + 1048576;
    const size_t setf = 1048576 + 1048576 + 2097152;      // 4.19M floats/set
    const bool split = ws_size >= (size_t)(2 * setf + 2097152) * 4;
    float* Qb = split ? (Va + 2097152) : Qa;
    float* Kb = split ? (Qb + 1048576) : Ka;
    float* Vb = split ? (Kb + 1048576) : Va;
    float* A  = (split ? (Vb + 2097152) : (Va + 2097152));

    const size_t lds_cross  = (size_t)(SEQ * DK + SEQ * DV) * 4;          // 24576
    const size_t lds_causal = lds_cross + (size_t)(33 * DV) * 4;          // 25632

    if (split) {
        // Stage 1: self-attention (causal multiplicative mask)
        proj_kernel<1><<<dim3(512), 256, 0, stream>>>(x, x, Wq, Wk, Wv,
                                                      Qa, Ka, Va, Qb, Kb, Vb);
        attn_kernel<1,1><<<dim3(BATCH * HEAD * 2), 128, lds_causal, stream>>>(
            Qa, Ka, Va, Qb, Kb, Vb, A);
        // Stage 2: cross-attention (same weights — faithful quirk)
        proj_kernel<1><<<dim3(512), 256, 0, stream>>>(A, xenc, Wq, Wk, Wv,
                                                      Qa, Ka, Va, Qb, Kb, Vb);
        attn_kernel<0,1><<<dim3(BATCH * HEAD * 2), 128, lds_cross, stream>>>(
            Qa, Ka, Va, Qb, Kb, Vb, A);
    } else {
        proj_kernel<0><<<dim3(256), 256, 0, stream>>>(x, x, Wq, Wk, Wv,
                                                      Qa, Ka, Va, Qb, Kb, Vb);
        attn_kernel<1,0><<<dim3(BATCH * HEAD * 2), 128, lds_causal, stream>>>(
            Qa, Ka, Va, Qb, Kb, Vb, A);
        proj_kernel<0><<<dim3(256), 256, 0, stream>>>(A, xenc, Wq, Wk, Wv,
                                                      Qa, Ka, Va, Qb, Kb, Vb);
        attn_kernel<0,0><<<dim3(BATCH * HEAD * 2), 128, lds_cross, stream>>>(
            Qa, Ka, Va, Qb, Kb, Vb, A);
    }

    // Stage 3: residual(x) + LayerNorm + MLP
    ln_mlp_kernel<<<dim3(BATCH * SEQ / 4), 256, 0, stream>>>(x, A, ln_g, ln_b,
                                                             w1, b1, w2, b2, out);
}